// Round 13
// baseline (2275.747 us; speedup 1.0000x reference)
//
#include <hip/hip_runtime.h>
#include <cmath>

// Problem constants (from reference)
#define NN  5      // N_NODES
#define BB  4      // batch
#define CCH 256    // channels
#define HWD 1024   // H*W
#define THRESH_V 0.3f
#define EPS_V 1e-12f

// R13 = R8's proven layouts + double-buffered KC=8 + ONE barrier per chunk +
// sched_barrier(0) fences so the compiler cannot sink the stage loads (R11's
// failure) or hoist the stage writes into the FMA block. Per chunk:
//   STAGE_LOAD(t+1) -> [fence] -> COMPUTE(buf t%2) -> [fence] ->
//   STAGE_WRITE(buf (t+1)%2) -> __syncthreads
// Global-load latency hides under 512 FMAs/wave; LDS-read pipe (~154us) and
// VALU (~160us) overlap instead of alternating.

#define CT 64      // channel rows per block
#define WT 64      // hw cols per block
#define KC 8       // k chunk
#define APAD 68    // As/W2s row stride (floats) - proven conflict level (R8)
#define SPAD 68    // Es row stride (floats) in epilogue

#define W2T_OFF (NN * CCH * CCH)      // second table in ws

// per-buffer layout (floats): Xs[5][8][64] @0 | As[8][68] @2560 | W2s @3104
#define ASO   2560
#define W2SO  (ASO + KC * APAD)       // 3104
#define BUFSZ (W2SO + KC * APAD)      // 3648
#define SMEM_FLOATS (2 * BUFSZ)       // 7296 floats = 29184 B (R8-equal)
// epilogue overlay Es[6][16][SPAD] = 6528 floats (fits)

// ---------------- prep: coalesced LDS-tile transpose (verified R12) ----------
// ws: At[i][k][c] = W1[i][c][k] + W2[i][c][k];  W2t[i][k][c] = W2[i][c][k]
__global__ void fub_prep(const float* __restrict__ conv_w, float* __restrict__ ws)
{
    __shared__ float Ta[64 * 68];
    __shared__ float Tw[64 * 68];
    const int u  = threadIdx.x;
    int bid = blockIdx.x;
    const int cb = bid & 3;  bid >>= 2;
    const int kb = bid & 3;  bid >>= 2;
    const int i  = bid;                   // 0..4

#pragma unroll
    for (int p = 0; p < 4; ++p) {
        const int cl = p * 16 + (u >> 4);
        const int kq = (u & 15) << 2;
        const float* g = conv_w + (size_t)(i * CCH + cb * 64 + cl) * (2 * CCH)
                       + kb * 64 + kq;
        const float4 w1 = *(const float4*)g;
        const float4 w2 = *(const float4*)(g + CCH);
        *(float4*)(Ta + cl * 68 + kq) =
            make_float4(w1.x + w2.x, w1.y + w2.y, w1.z + w2.z, w1.w + w2.w);
        *(float4*)(Tw + cl * 68 + kq) = w2;
    }
    __syncthreads();

#pragma unroll
    for (int p = 0; p < 4; ++p) {
        const int kl = p * 16 + (u >> 4);
        const int cq = (u & 15) << 2;
        float4 va, vw;
        va.x = Ta[(cq + 0) * 68 + kl];  vw.x = Tw[(cq + 0) * 68 + kl];
        va.y = Ta[(cq + 1) * 68 + kl];  vw.y = Tw[(cq + 1) * 68 + kl];
        va.z = Ta[(cq + 2) * 68 + kl];  vw.z = Tw[(cq + 2) * 68 + kl];
        va.w = Ta[(cq + 3) * 68 + kl];  vw.w = Tw[(cq + 3) * 68 + kl];
        float* o = ws + (size_t)(i * CCH + kb * 64 + kl) * CCH + cb * 64 + cq;
        *(float4*)o = va;
        *(float4*)(o + W2T_OFF) = vw;
    }
}

// ---------------- main ----------------
__global__ __launch_bounds__(384, 3)
void fub_main(const float* __restrict__ x, const float* __restrict__ wmat,
              const float* __restrict__ ws, const float* __restrict__ conv_b,
              float* __restrict__ out)
{
    __shared__ __align__(16) float smem[SMEM_FLOATS];
    float* Es = smem;                  // [6][16][SPAD] overlay (epilogue only)

    const int tid  = threadIdx.x;
    const int wv   = tid >> 6;        // 0..5 : stream id
    const int lane = tid & 63;

    // XCD-chunked bijective swizzle (1280 % 8 == 0)
    const int wg  = blockIdx.x;
    int L = (wg & 7) * 160 + (wg >> 3);
    const int i   = L % 5;  L /= 5;
    const int ct  = L & 3;  L >>= 2;
    const int b   = L & 3;  L >>= 2;
    const int hwt = L;                 // 0..15

    const int c0  = ct * CT;
    const int hw0 = hwt * WT;

    const int lr = (lane >> 3) << 3;  // frag row base 0,8,...,56
    const int lc = (lane & 7)  << 3;  // frag col base 0,8,...,56

    // stream w<5: A_i @ x[w]; stream 5: W2_i @ x[i]
    const int jx    = (wv < NN) ? wv : i;
    const int msoff = (wv == 5) ? W2SO : ASO;
    const float* Mb = smem + msoff + lr;
    const float* Xb = smem + jx * (KC * WT) + lc;

    // ---- staging roles: threads 0..319 stage X (2 float4), 320..383 A/W2 (4) ----
    const bool xrole = (tid < 320);
    const float *p0, *p1;             // rolling global pointers
    int l0, l1, l2, l3;               // LDS float-offsets within a buffer
    if (xrole) {
        const int i0 = tid,       j0 = i0 >> 7, r0 = i0 & 127;
        const int i1 = tid + 320, j1 = i1 >> 7, r1 = i1 & 127;
        const int k0r = r0 >> 4, q0 = (r0 & 15) << 2;
        const int k1r = r1 >> 4, q1 = (r1 & 15) << 2;
        p0 = x + ((size_t)(j0 * BB + b) * CCH + k0r) * HWD + hw0 + q0;
        p1 = x + ((size_t)(j1 * BB + b) * CCH + k1r) * HWD + hw0 + q1;
        l0 = j0 * (KC * WT) + k0r * WT + q0;
        l1 = j1 * (KC * WT) + k1r * WT + q1;
        l2 = l3 = 0;
    } else {
        const int u  = tid - 320;            // 0..63
        const int ka = u >> 4;               // 0..3
        const int c4 = (u & 15) << 2;        // 0..60
        p0 = ws + ((size_t)(i * CCH) + ka) * CCH + c0 + c4;          // A rows ka, ka+4
        p1 = p0 + W2T_OFF;                                           // W2 rows
        l0 = ASO  + ka * APAD + c4;
        l1 = ASO  + (ka + 4) * APAD + c4;
        l2 = W2SO + ka * APAD + c4;
        l3 = W2SO + (ka + 4) * APAD + c4;
    }

    float4 s0, s1, s2, s3;

#define STAGE_LOAD() do {                                               \
        if (xrole) {                                                    \
            s0 = *(const float4*)p0;  s1 = *(const float4*)p1;          \
            p0 += KC * HWD;           p1 += KC * HWD;                   \
        } else {                                                        \
            s0 = *(const float4*)p0;  s1 = *(const float4*)(p0 + 4 * CCH); \
            s2 = *(const float4*)p1;  s3 = *(const float4*)(p1 + 4 * CCH); \
            p0 += KC * CCH;           p1 += KC * CCH;                   \
        }                                                               \
    } while (0)

#define STAGE_WRITE(BO) do {                                            \
        if (xrole) {                                                    \
            *(float4*)(smem + (BO) + l0) = s0;                          \
            *(float4*)(smem + (BO) + l1) = s1;                          \
        } else {                                                        \
            *(float4*)(smem + (BO) + l0) = s0;                          \
            *(float4*)(smem + (BO) + l1) = s1;                          \
            *(float4*)(smem + (BO) + l2) = s2;                          \
            *(float4*)(smem + (BO) + l3) = s3;                          \
        }                                                               \
    } while (0)

    float acc[8][8];
#pragma unroll
    for (int r = 0; r < 8; ++r)
#pragma unroll
        for (int c = 0; c < 8; ++c) acc[r][c] = 0.0f;

#define COMPUTE(BO) do {                                                \
        _Pragma("unroll")                                               \
        for (int kk = 0; kk < KC; ++kk) {                               \
            const float4 a0 = *(const float4*)(Mb + (BO) + kk * APAD);      \
            const float4 a1 = *(const float4*)(Mb + (BO) + kk * APAD + 4);  \
            const float4 x0 = *(const float4*)(Xb + (BO) + kk * WT);        \
            const float4 x1 = *(const float4*)(Xb + (BO) + kk * WT + 4);    \
            const float ar[8] = {a0.x,a0.y,a0.z,a0.w,a1.x,a1.y,a1.z,a1.w};  \
            const float xc[8] = {x0.x,x0.y,x0.z,x0.w,x1.x,x1.y,x1.z,x1.w};  \
            _Pragma("unroll")                                           \
            for (int r = 0; r < 8; ++r)                                 \
                _Pragma("unroll")                                       \
                for (int c = 0; c < 8; ++c)                             \
                    acc[r][c] = fmaf(ar[r], xc[c], acc[r][c]);          \
        }                                                               \
    } while (0)

    // prologue: chunk 0 -> buffer 0
    STAGE_LOAD();
    STAGE_WRITE(0);
    __syncthreads();

    // 32 chunks, parity-unrolled, ONE barrier per chunk.
    // Fences pin: loads issued before FMAs; ds_writes after FMAs.
#pragma unroll 1
    for (int t = 0; t < 32; t += 2) {
        STAGE_LOAD();                              // chunk t+1 -> regs
        __builtin_amdgcn_sched_barrier(0);
        COMPUTE(0);
        __builtin_amdgcn_sched_barrier(0);
        STAGE_WRITE(BUFSZ);
        __syncthreads();

        if (t < 30) STAGE_LOAD();                  // chunk t+2 -> regs
        __builtin_amdgcn_sched_barrier(0);
        COMPUTE(BUFSZ);
        __builtin_amdgcn_sched_barrier(0);
        if (t < 30) STAGE_WRITE(0);
        __syncthreads();
    }

    // ---- epilogue: 4 passes over 16-row bands; exchange streams via LDS ----
    const int rhme  = lr >> 4;
    const int rbase = lr & 15;

    float wrow[NN];
#pragma unroll
    for (int j = 0; j < NN; ++j) wrow[j] = wmat[i * NN + j];

#pragma unroll
    for (int rh = 0; rh < 4; ++rh) {
        if (rhme == rh) {
            float* Eb = Es + wv * (16 * SPAD) + lc;
#pragma unroll
            for (int r = 0; r < 8; ++r) {
                *(float4*)(Eb + (rbase + r) * SPAD) =
                    make_float4(acc[r][0], acc[r][1], acc[r][2], acc[r][3]);
                *(float4*)(Eb + (rbase + r) * SPAD + 4) =
                    make_float4(acc[r][4], acc[r][5], acc[r][6], acc[r][7]);
            }
        }
        __syncthreads();

        if (tid < 256) {
            const int row  = tid >> 4;           // 0..15
            const int colq = (tid & 15) << 2;    // 0..60
            const int c    = c0 + rh * 16 + row;
            const float bias = conv_b[i * CCH + c];

            const float4 T = *(const float4*)(Es + 5 * (16 * SPAD) + row * SPAD + colq);
            const float Tv[4] = {T.x, T.y, T.z, T.w};

            float num[4] = {0.f, 0.f, 0.f, 0.f};
            float sq [4] = {0.f, 0.f, 0.f, 0.f};
#pragma unroll
            for (int j = 0; j < NN; ++j) {
                const float4 s  = *(const float4*)(Es + j * (16 * SPAD) + row * SPAD + colq);
                const float4 xj = *(const float4*)(
                    x + (size_t)((j * BB + b) * CCH + c) * HWD + hw0 + colq);
                const float sv[4] = {s.x, s.y, s.z, s.w};
                const float xv[4] = {xj.x, xj.y, xj.z, xj.w};
#pragma unroll
                for (int cc = 0; cc < 4; ++cc) {
                    const float target = sv[cc] + Tv[cc] + bias;
                    const float dist   = xv[cc] - target;
                    const float z      = dist * wrow[j];
                    float e = 1.0f / (1.0f + expf(-z));
                    e = (e > THRESH_V) ? e : 0.0f;
                    sq[cc]  = fmaf(e, e, sq[cc]);
                    num[cc] = fmaf(e, xv[cc], num[cc]);
                }
            }
            float4 res;
            res.x = num[0] / fmaxf(sqrtf(sq[0]), EPS_V);
            res.y = num[1] / fmaxf(sqrtf(sq[1]), EPS_V);
            res.z = num[2] / fmaxf(sqrtf(sq[2]), EPS_V);
            res.w = num[3] / fmaxf(sqrtf(sq[3]), EPS_V);
            *(float4*)(out + (size_t)((i * BB + b) * CCH + c) * HWD + hw0 + colq) = res;
        }
        __syncthreads();
    }
}

extern "C" void kernel_launch(void* const* d_in, const int* in_sizes, int n_in,
                              void* d_out, int out_size, void* d_ws, size_t ws_size,
                              hipStream_t stream) {
    const float* x      = (const float*)d_in[0];
    const float* w      = (const float*)d_in[1];
    const float* conv_w = (const float*)d_in[2];
    const float* conv_b = (const float*)d_in[3];
    float* out = (float*)d_out;
    float* ws  = (float*)d_ws;   // needs 2*5*256*256*4 B = 2.62 MB

    // prep: 5 i x 4 kb x 4 cb tiles, LDS transpose, coalesced both sides
    fub_prep<<<dim3(80), dim3(256), 0, stream>>>(conv_w, ws);

    // grid: hwt(16) * b(4) * ct(4) * i(5) = 1280 blocks of 384 threads
    fub_main<<<dim3(1280), dim3(384), 0, stream>>>(x, w, ws, conv_b, out);
}

// Round 15
// 710.752 us; speedup vs baseline: 3.2019x; 3.2019x over previous
//
#include <hip/hip_runtime.h>
#include <cmath>

// Problem constants (from reference)
#define NN  5      // N_NODES
#define BB  4      // batch
#define CCH 256    // channels
#define HWD 1024   // H*W
#define THRESH_V 0.3f
#define EPS_V 1e-12f
#define GUARD 3e-4f   // |e-0.3| guard band for fp32 recompute (300x worst error)

// R15 = R14 (6-term bf16-split MFMA, AGPR accumulator, no LDS/barriers in
// K-loop) + THE FIX: near-threshold edges (|e-0.3| < GUARD) are recomputed in
// fp32 with arithmetic BIT-IDENTICAL to the proven-passing fp32 kernel
// (k-sequential fmaf, (S+T)+bias, same expf), reading conv_w/x directly.
// Recomputed edges flip exactly as the 0.0156-absmax kernel; others are
// > GUARD from the threshold with MFMA error ~1e-6 -> cannot flip. ~10^-4 of
// edges recompute (~2 per epilogue wave): correctness decoupled from split
// residual at ~5us cost. R14 confirmed ws_size >= 35.4MB (MFMA path ran).

typedef __attribute__((ext_vector_type(8))) short          bf16x8;
typedef __attribute__((ext_vector_type(8))) unsigned short u16x8;
typedef __attribute__((ext_vector_type(4))) float          f32x4;

// ---- MFMA frag tables in ws (units: u16x8 = one lane's 16B of a frag) ----
//   A table: [i][m(0=A,1=W2)][hl(3)][mg(16)][kst(8)] x 64 lanes
//   X table: [j][b][hl(3)][pg(64)][kst(8)] x 64 lanes
#define AUNITS      (NN * 2 * 3 * 16 * 8 * 64)   // 245760  (3.93 MB)
#define XBASE       AUNITS
#define XUNITS      (NN * BB * 3 * 64 * 8 * 64)  // 1966080 (31.5 MB)
#define WS_MFMA_BYTES ((size_t)(AUNITS + XUNITS) * 16)   // 35.4 MB

#define SPAD 68
#define ES_FLOATS (6 * 32 * SPAD)                // 13056 floats = 52.2 KB

__device__ __forceinline__ unsigned short f2bf(float f) {
    unsigned int u = __float_as_uint(f);
    unsigned int r = (u + 0x7fffu + ((u >> 16) & 1u)) >> 16;   // RNE
    return (unsigned short)r;
}
__device__ __forceinline__ float bf2f(unsigned short h) {
    return __uint_as_float(((unsigned int)h) << 16);
}
__device__ __forceinline__ void split3(float v, unsigned short& h,
                                       unsigned short& m, unsigned short& l) {
    h = f2bf(v);
    const float r1 = v - bf2f(h);
    m = f2bf(r1);
    const float r2 = r1 - bf2f(m);
    l = f2bf(r2);
}

// Exact-e recompute: bit-identical arithmetic to the passing fp32 kernel.
__device__ __attribute__((noinline))
float exact_e(const float* __restrict__ x, const float* __restrict__ conv_w,
              int i, int jn, int b, int c, int hw, float bias, float wij)
{
    const float* cw = conv_w + (size_t)(i * CCH + c) * (2 * CCH);
    const float* xj = x + (size_t)((jn * BB + b) * CCH) * HWD + hw;
    const float* xi = x + (size_t)((i  * BB + b) * CCH) * HWD + hw;
    float S = 0.f, T = 0.f;
    for (int k = 0; k < CCH; ++k) {
        const float A = cw[k] + cw[CCH + k];           // = prep's w1+w2, same rounding
        S = fmaf(A,            xj[(size_t)k * HWD], S);
        T = fmaf(cw[CCH + k],  xi[(size_t)k * HWD], T);
    }
    const float xv     = xj[(size_t)c * HWD];          // x[jn,b,c,hw]
    const float target = S + T + bias;                 // (S+T)+bias, as fp32 kernel
    const float dist   = xv - target;
    const float z      = dist * wij;
    return 1.0f / (1.0f + expf(-z));
}

// ---------------- prep A: conv_w -> A/W2 h/m/l frag tables ----------------
__global__ void fub_prep_a6(const float* __restrict__ conv_w, u16x8* __restrict__ W)
{
    const int t = blockIdx.x * 256 + threadIdx.x;      // 0..40959
    if (t >= NN * 16 * 8 * 64) return;
    const int lane  = t & 63;
    const int kst   = (t >> 6) & 7;
    const int mg    = (t >> 9) & 15;
    const int i     = t >> 13;

    const int c  = mg * 16 + (lane & 15);
    const int kb = kst * 32 + 8 * (lane >> 4);

    u16x8 A[3], Wv[3];
#pragma unroll
    for (int jj = 0; jj < 8; ++jj) {
        const float* p = conv_w + (size_t)(i * CCH + c) * (2 * CCH) + kb + jj;
        const float w1 = p[0];
        const float w2 = p[CCH];
        unsigned short h, m, l;
        split3(w1 + w2, h, m, l);
        A[0][jj] = h; A[1][jj] = m; A[2][jj] = l;
        split3(w2, h, m, l);
        Wv[0][jj] = h; Wv[1][jj] = m; Wv[2][jj] = l;
    }
#pragma unroll
    for (int hl = 0; hl < 3; ++hl) {
        const int fA = (((i * 2 + 0) * 3 + hl) * 16 + mg) * 8 + kst;
        const int fW = (((i * 2 + 1) * 3 + hl) * 16 + mg) * 8 + kst;
        W[fA * 64 + lane] = A[hl];
        W[fW * 64 + lane] = Wv[hl];
    }
}

// ---------------- prep X: x -> h/m/l B-frag tables ----------------
__global__ void fub_prep_x6(const float* __restrict__ x, u16x8* __restrict__ W)
{
    const int t = blockIdx.x * 256 + threadIdx.x;      // 0..655359
    const int lane = t & 63;
    const int kst  = (t >> 6) & 7;
    const int pg   = (t >> 9) & 63;
    const int b    = (t >> 15) & 3;
    const int j    = t >> 17;
    if (j >= NN) return;

    const int p  = pg * 16 + (lane & 15);
    const int kb = kst * 32 + 8 * (lane >> 4);

    u16x8 X[3];
#pragma unroll
    for (int jj = 0; jj < 8; ++jj) {
        const float v = x[(size_t)((j * BB + b) * CCH + kb + jj) * HWD + p];
        unsigned short h, m, l;
        split3(v, h, m, l);
        X[0][jj] = h; X[1][jj] = m; X[2][jj] = l;
    }
#pragma unroll
    for (int hl = 0; hl < 3; ++hl) {
        const int f = (((j * BB + b) * 3 + hl) * 64 + pg) * 8 + kst;
        W[XBASE + f * 64 + lane] = X[hl];
    }
}

// ---------------- MFMA main ----------------
__global__ __launch_bounds__(384, 2)
void fub_main_mfma(const float* __restrict__ x, const float* __restrict__ wmat,
                   const bf16x8* __restrict__ AT, const float* __restrict__ conv_b,
                   const float* __restrict__ conv_w, float* __restrict__ out)
{
    __shared__ __align__(16) float Es[ES_FLOATS];   // [6][32][SPAD]

    const int tid  = threadIdx.x;
    const int wv   = tid >> 6;        // 0..5 : stream id
    const int lane = tid & 63;

    // XCD-chunked bijective swizzle (1280 % 8 == 0)
    const int wg  = blockIdx.x;
    int L = (wg & 7) * 160 + (wg >> 3);
    const int i   = L % 5;  L /= 5;
    const int ct  = L & 3;  L >>= 2;
    const int b   = L & 3;  L >>= 2;
    const int hwt = L;                 // 0..15

    const int c0  = ct * 64;
    const int hw0 = hwt * 64;
    const int mg0 = ct * 4;
    const int pg0 = hwt * 4;

    // stream w<5: A_i @ x[w]; stream 5: W2_i @ x[i]
    const int m  = (wv == 5) ? 1 : 0;
    const int jx = (wv < NN) ? wv : i;

    // unit-index bases (lane folded); strides: A hl=8192, X hl=32768
    const int baseA = ((((i * 2 + m) * 3 + 0) * 16 + mg0) * 8) * 64 + lane;
    const int baseX = XBASE + ((((jx * BB + b) * 3 + 0) * 64 + pg0) * 8) * 64 + lane;

    f32x4 acc[4][4];
#pragma unroll
    for (int mf = 0; mf < 4; ++mf)
#pragma unroll
        for (int nf = 0; nf < 4; ++nf) acc[mf][nf] = (f32x4){0.f, 0.f, 0.f, 0.f};

#pragma unroll 1
    for (int kst = 0; kst < 8; ++kst) {
        bf16x8 xh[4], xm[4], xl[4];
#pragma unroll
        for (int f = 0; f < 4; ++f) {
            const int o = (f * 8 + kst) * 64;
            xh[f] = AT[baseX + o];
            xm[f] = AT[baseX + 32768 + o];
            xl[f] = AT[baseX + 65536 + o];
        }
#pragma unroll
        for (int mf = 0; mf < 4; ++mf) {
            const int o = (mf * 8 + kst) * 64;
            const bf16x8 ah = AT[baseA + o];
            const bf16x8 am = AT[baseA + 8192 + o];
            const bf16x8 al = AT[baseA + 16384 + o];
#pragma unroll
            for (int nf = 0; nf < 4; ++nf) {
                f32x4 a = acc[mf][nf];
                a = __builtin_amdgcn_mfma_f32_16x16x32_bf16(ah, xh[nf], a, 0, 0, 0);
                a = __builtin_amdgcn_mfma_f32_16x16x32_bf16(am, xh[nf], a, 0, 0, 0);
                a = __builtin_amdgcn_mfma_f32_16x16x32_bf16(ah, xm[nf], a, 0, 0, 0);
                a = __builtin_amdgcn_mfma_f32_16x16x32_bf16(am, xm[nf], a, 0, 0, 0);
                a = __builtin_amdgcn_mfma_f32_16x16x32_bf16(ah, xl[nf], a, 0, 0, 0);
                a = __builtin_amdgcn_mfma_f32_16x16x32_bf16(al, xh[nf], a, 0, 0, 0);
                acc[mf][nf] = a;
            }
        }
    }

    // ---- epilogue: 2 passes over 32-row bands + guarded fp32 recompute ----
    float wrow[NN];
#pragma unroll
    for (int j = 0; j < NN; ++j) wrow[j] = wmat[i * NN + j];

    const int g16 = lane >> 4;          // 0..3
    const int n16 = lane & 15;          // 0..15

#pragma unroll
    for (int rh = 0; rh < 2; ++rh) {
        // write band rh (frags mf = 2rh, 2rh+1); D: col=n16, row=4*g16+reg
#pragma unroll
        for (int mh = 0; mh < 2; ++mh) {
            const int mf = 2 * rh + mh;
            float* Eb = Es + wv * (32 * SPAD) + (mh * 16 + 4 * g16) * SPAD + n16;
#pragma unroll
            for (int nf = 0; nf < 4; ++nf) {
                const f32x4 v = acc[mf][nf];
                float* E = Eb + nf * 16;
                E[0 * SPAD] = v.x;
                E[1 * SPAD] = v.y;
                E[2 * SPAD] = v.z;
                E[3 * SPAD] = v.w;
            }
        }
        __syncthreads();

        if (tid < 256) {
            const int row  = tid >> 3;           // 0..31
            const int col8 = (tid & 7) << 3;     // 0..56
            const int c    = c0 + rh * 32 + row;
            const float bias = conv_b[i * CCH + c];

#pragma unroll
            for (int h = 0; h < 2; ++h) {
                const int colq = col8 + 4 * h;

                const float4 T = *(const float4*)(Es + 5 * (32 * SPAD) + row * SPAD + colq);
                const float Tv[4] = {T.x, T.y, T.z, T.w};

                float num[4] = {0.f, 0.f, 0.f, 0.f};
                float sq [4] = {0.f, 0.f, 0.f, 0.f};
#pragma unroll
                for (int j = 0; j < NN; ++j) {
                    const float4 s  = *(const float4*)(Es + j * (32 * SPAD) + row * SPAD + colq);
                    const float4 xj = *(const float4*)(
                        x + (size_t)((j * BB + b) * CCH + c) * HWD + hw0 + colq);
                    const float sv[4] = {s.x, s.y, s.z, s.w};
                    const float xv[4] = {xj.x, xj.y, xj.z, xj.w};
#pragma unroll
                    for (int cc = 0; cc < 4; ++cc) {
                        const float target = sv[cc] + Tv[cc] + bias;
                        const float dist   = xv[cc] - target;
                        const float z      = dist * wrow[j];
                        float e = 1.0f / (1.0f + expf(-z));
                        if (__builtin_expect(fabsf(e - THRESH_V) < GUARD, 0)) {
                            // near-threshold: fp32 recompute, bit-identical to
                            // the passing fp32 kernel's arithmetic
                            e = exact_e(x, conv_w, i, j, b, c,
                                        hw0 + colq + cc, bias, wrow[j]);
                        }
                        e = (e > THRESH_V) ? e : 0.0f;
                        sq[cc]  = fmaf(e, e, sq[cc]);
                        num[cc] = fmaf(e, xv[cc], num[cc]);
                    }
                }
                float4 res;
                res.x = num[0] / fmaxf(sqrtf(sq[0]), EPS_V);
                res.y = num[1] / fmaxf(sqrtf(sq[1]), EPS_V);
                res.z = num[2] / fmaxf(sqrtf(sq[2]), EPS_V);
                res.w = num[3] / fmaxf(sqrtf(sq[3]), EPS_V);
                *(float4*)(out + (size_t)((i * BB + b) * CCH + c) * HWD + hw0 + colq) =
                    res;
            }
        }
        __syncthreads();
    }
}

// ================= R8 fallback (proven 290us) — used if ws too small ========
#define CT 64
#define WT 64
#define KC 16
#define APAD 68
#define W2T_OFF (NN * CCH * CCH)
#define XS_FLOATS (NN * KC * WT)
#define AS_OFF    XS_FLOATS
#define W2S_OFF   (AS_OFF + KC * APAD)
#define SMEM_FLOATS (W2S_OFF + KC * APAD)

__global__ void fub_prep(const float* __restrict__ conv_w, float* __restrict__ ws)
{
    const int t = blockIdx.x * 256 + threadIdx.x;
    if (t >= NN * CCH * 64) return;
    const int c4 = (t & 63) << 2;
    const int k  = (t >> 6) & 255;
    const int i  = t >> 14;
    float s1[4], s2[4];
#pragma unroll
    for (int cc = 0; cc < 4; ++cc) {
        const float* p = conv_w + (size_t)(i * CCH + c4 + cc) * (2 * CCH) + k;
        const float w1 = p[0];
        const float w2 = p[CCH];
        s1[cc] = w1 + w2;
        s2[cc] = w2;
    }
    float* At  = ws + (size_t)(i * CCH + k) * CCH + c4;
    float* W2t = ws + W2T_OFF + (size_t)(i * CCH + k) * CCH + c4;
    *(float4*)At  = make_float4(s1[0], s1[1], s1[2], s1[3]);
    *(float4*)W2t = make_float4(s2[0], s2[1], s2[2], s2[3]);
}

__global__ __launch_bounds__(384, 3)
void fub_main_r8(const float* __restrict__ x, const float* __restrict__ wmat,
                 const float* __restrict__ ws, const float* __restrict__ conv_b,
                 float* __restrict__ out)
{
    __shared__ __align__(16) float smem[SMEM_FLOATS];
    float* Xs  = smem;
    float* As  = smem + AS_OFF;
    float* W2s = smem + W2S_OFF;
    float* Es  = smem;

    const int tid  = threadIdx.x;
    const int wv   = tid >> 6;
    const int lane = tid & 63;

    const int wg  = blockIdx.x;
    int L = (wg & 7) * 160 + (wg >> 3);
    const int i   = L % 5;  L /= 5;
    const int ct  = L & 3;  L >>= 2;
    const int b   = L & 3;  L >>= 2;
    const int hwt = L;

    const int c0  = ct * CT;
    const int hw0 = hwt * WT;

    const int lr = (lane >> 3) << 3;
    const int lc = (lane & 7)  << 3;

    const int jx = (wv < NN) ? wv : i;
    const float* Ms = (wv == 5) ? W2s : As;
    const float* Mb = Ms + lr;
    const float* Xb = Xs + jx * (KC * WT) + lc;

    float acc[8][8];
#pragma unroll
    for (int r = 0; r < 8; ++r)
#pragma unroll
        for (int c = 0; c < 8; ++c) acc[r][c] = 0.0f;

    for (int k0 = 0; k0 < CCH; k0 += KC) {
        if (tid < 256) {
#pragma unroll
            for (int it = 0; it < 5; ++it) {
                const int t   = tid + it * 256;
                const int j   = t >> 8;
                const int rem = t & 255;
                const int kk  = rem >> 4;
                const int q4  = (rem & 15) << 2;
                const float4 v = *(const float4*)(
                    x + (size_t)((j * BB + b) * CCH + k0 + kk) * HWD + hw0 + q4);
                *(float4*)(Xs + j * (KC * WT) + kk * WT + q4) = v;
            }
        } else {
            const int u = tid - 256;
#pragma unroll
            for (int it = 0; it < 4; ++it) {
                const int t   = u + it * 128;
                const int tbl = t >> 8;
                const int rem = t & 255;
                const int kk  = rem >> 4;
                const int c4  = (rem & 15) << 2;
                const float4 v = *(const float4*)(
                    ws + (size_t)(tbl ? W2T_OFF : 0)
                       + (size_t)(i * CCH + k0 + kk) * CCH + c0 + c4);
                *(float4*)((tbl ? W2s : As) + kk * APAD + c4) = v;
            }
        }
        __syncthreads();

#pragma unroll 4
        for (int kk = 0; kk < KC; ++kk) {
            const float4 a0 = *(const float4*)(Mb + kk * APAD);
            const float4 a1 = *(const float4*)(Mb + kk * APAD + 4);
            const float4 x0 = *(const float4*)(Xb + kk * WT);
            const float4 x1 = *(const float4*)(Xb + kk * WT + 4);
            const float ar[8] = {a0.x, a0.y, a0.z, a0.w, a1.x, a1.y, a1.z, a1.w};
            const float xc[8] = {x0.x, x0.y, x0.z, x0.w, x1.x, x1.y, x1.z, x1.w};
#pragma unroll
            for (int r = 0; r < 8; ++r)
#pragma unroll
                for (int c = 0; c < 8; ++c)
                    acc[r][c] = fmaf(ar[r], xc[c], acc[r][c]);
        }
        __syncthreads();
    }

    const int rhme  = lr >> 4;
    const int rbase = lr & 15;

    float wrow[NN];
#pragma unroll
    for (int j = 0; j < NN; ++j) wrow[j] = wmat[i * NN + j];

#pragma unroll
    for (int rh = 0; rh < 4; ++rh) {
        if (rhme == rh) {
            float* Eb = Es + wv * (16 * SPAD) + lc;
#pragma unroll
            for (int r = 0; r < 8; ++r) {
                *(float4*)(Eb + (rbase + r) * SPAD) =
                    make_float4(acc[r][0], acc[r][1], acc[r][2], acc[r][3]);
                *(float4*)(Eb + (rbase + r) * SPAD + 4) =
                    make_float4(acc[r][4], acc[r][5], acc[r][6], acc[r][7]);
            }
        }
        __syncthreads();

        if (tid < 256) {
            const int row  = tid >> 4;
            const int colq = (tid & 15) << 2;
            const int c    = c0 + rh * 16 + row;
            const float bias = conv_b[i * CCH + c];

            const float4 T = *(const float4*)(Es + 5 * (16 * SPAD) + row * SPAD + colq);
            const float Tv[4] = {T.x, T.y, T.z, T.w};

            float num[4] = {0.f, 0.f, 0.f, 0.f};
            float sq [4] = {0.f, 0.f, 0.f, 0.f};
#pragma unroll
            for (int j = 0; j < NN; ++j) {
                const float4 s  = *(const float4*)(Es + j * (16 * SPAD) + row * SPAD + colq);
                const float4 xj = *(const float4*)(
                    x + (size_t)((j * BB + b) * CCH + c) * HWD + hw0 + colq);
                const float sv[4] = {s.x, s.y, s.z, s.w};
                const float xv[4] = {xj.x, xj.y, xj.z, xj.w};
#pragma unroll
                for (int cc = 0; cc < 4; ++cc) {
                    const float target = sv[cc] + Tv[cc] + bias;
                    const float dist   = xv[cc] - target;
                    const float z      = dist * wrow[j];
                    float e = 1.0f / (1.0f + expf(-z));
                    e = (e > THRESH_V) ? e : 0.0f;
                    sq[cc]  = fmaf(e, e, sq[cc]);
                    num[cc] = fmaf(e, xv[cc], num[cc]);
                }
            }
            float4 res;
            res.x = num[0] / fmaxf(sqrtf(sq[0]), EPS_V);
            res.y = num[1] / fmaxf(sqrtf(sq[1]), EPS_V);
            res.z = num[2] / fmaxf(sqrtf(sq[2]), EPS_V);
            res.w = num[3] / fmaxf(sqrtf(sq[3]), EPS_V);
            *(float4*)(out + (size_t)((i * BB + b) * CCH + c) * HWD + hw0 + colq) = res;
        }
        __syncthreads();
    }
}

extern "C" void kernel_launch(void* const* d_in, const int* in_sizes, int n_in,
                              void* d_out, int out_size, void* d_ws, size_t ws_size,
                              hipStream_t stream) {
    const float* x      = (const float*)d_in[0];
    const float* w      = (const float*)d_in[1];
    const float* conv_w = (const float*)d_in[2];
    const float* conv_b = (const float*)d_in[3];
    float* out = (float*)d_out;

    if (ws_size >= WS_MFMA_BYTES) {
        u16x8* W = (u16x8*)d_ws;
        fub_prep_a6<<<dim3(160),  dim3(256), 0, stream>>>(conv_w, W);
        fub_prep_x6<<<dim3(2560), dim3(256), 0, stream>>>(x, W);
        fub_main_mfma<<<dim3(1280), dim3(384), 0, stream>>>(
            x, w, (const bf16x8*)d_ws, conv_b, conv_w, out);
    } else {
        float* ws = (float*)d_ws;   // needs 2.62 MB
        fub_prep<<<dim3(320), dim3(256), 0, stream>>>(conv_w, ws);
        fub_main_r8<<<dim3(1280), dim3(384), 0, stream>>>(x, w, ws, conv_b, out);
    }
}